// Round 5
// baseline (112.087 us; speedup 1.0000x reference)
//
#include <hip/hip_runtime.h>

#define NB 64
#define NC 206
#define N (NB * NC)        // 13184
#define IPT 4              // positives per thread (256 thr -> 1024 i per x-row)
#define GX 13              // ceil(N / 1024) worst-case positive coverage
#define GY 96              // group-chunk splits
#define NBLK (GX * GY)     // 1248
#define MAXG 3328          // worst-case groups: 64 * ceil(206/4)
#define MAXCHUNK 35        // ceil(MAXG / GY)
#define LN2F 0.69314718056f

// Workspace. Poisoned once to 0xAA by harness; every field we read is
// rewritten by prep/pairs on every call.
struct Ws {
    float2 pos[N];            // compacted positives {exp(-p), w}
    float  EG[MAXG * 4];      // grouped negative exp(p), zero-padded to 4
    float  WG[MAXG];          // per-group weight * ln2
    unsigned int npos, nneg, ngroups, done;
    double partials[NBLK];
};

// ---- single-block deterministic prep: compact + transform + group ----
__global__ __launch_bounds__(1024) void prep_kernel(
    const float* __restrict__ preds,
    const float* __restrict__ sw,
    const int* __restrict__ labels,
    Ws* __restrict__ ws)
{
    const int wave = threadIdx.x >> 6;   // 0..15
    const int lane = threadIdx.x & 63;

    __shared__ int rowPos[NB], rowNeg[NB];
    __shared__ int posBase[NB], grpBase[NB];
    __shared__ unsigned int totals[3];   // npos, nneg, ngroups

    // phase 1: per-row counts (wave w owns rows w, w+16, ...)
    for (int r = wave; r < NB; r += 16) {
        int pc = 0, nc = 0;
        for (int c0 = 0; c0 < NC; c0 += 64) {
            int c = c0 + lane;
            int l = (c < NC) ? labels[r * NC + c] : -1;
            pc += __popcll(__ballot(l == 1));
            nc += __popcll(__ballot(l == 0));
        }
        if (lane == 0) { rowPos[r] = pc; rowNeg[r] = nc; }
    }
    __syncthreads();

    // phase 2: exclusive scans over 64 rows by wave 0
    if (wave == 0) {
        int pc = rowPos[lane];
        int nc = rowNeg[lane];
        int gc = (nc + 3) >> 2;
        int ip = pc, in_ = nc, ig = gc;
        #pragma unroll
        for (int off = 1; off < 64; off <<= 1) {
            int tp = __shfl_up(ip, off, 64);
            int tn = __shfl_up(in_, off, 64);
            int tg = __shfl_up(ig, off, 64);
            if (lane >= off) { ip += tp; in_ += tn; ig += tg; }
        }
        posBase[lane] = ip - pc;
        grpBase[lane] = ig - gc;
        if (lane == 63) { totals[0] = ip; totals[1] = in_; totals[2] = ig; }
    }
    __syncthreads();
    if (threadIdx.x == 0) {
        ws->npos    = totals[0];
        ws->nneg    = totals[1];
        ws->ngroups = totals[2];
        ws->done    = 0;          // ticket counter for pairs' final reduce
    }

    // phase 3: ordered writes
    for (int r = wave; r < NB; r += 16) {
        const float w    = sw[r];
        const float wln2 = w * LN2F;
        int pOff = posBase[r];
        int nIdx = 0;
        const int gBase = grpBase[r];
        for (int c0 = 0; c0 < NC; c0 += 64) {
            int c = c0 + lane;
            bool inb = (c < NC);
            float p = inb ? preds[r * NC + c] : 0.0f;
            int   l = inb ? labels[r * NC + c] : -1;
            unsigned long long balP = __ballot(l == 1);
            unsigned long long balN = __ballot(l == 0);
            unsigned long long pre  = (1ull << lane) - 1ull;
            if (l == 1) {
                int o = pOff + __popcll(balP & pre);
                ws->pos[o] = make_float2(__expf(-p), w);
            }
            if (l == 0) {
                int idx = nIdx + __popcll(balN & pre);
                int g   = gBase + (idx >> 2);
                ws->EG[g * 4 + (idx & 3)] = __expf(p);
                if ((idx & 3) == 0) ws->WG[g] = wln2;
            }
            pOff += __popcll(balP);
            nIdx += __popcll(balN);
        }
        // zero-pad the row's last group (E=0 -> t=1 -> log contribution 0)
        int fill = nIdx & 3;
        if (fill) {
            int gLast = gBase + (nIdx >> 2);
            if (lane < 4 - fill) ws->EG[gLast * 4 + fill + lane] = 0.0f;
        }
    }
}

// ---- pairs + fused final reduction (ticket: last block finalizes) ----
__global__ __launch_bounds__(256) void pairs_kernel(
    Ws* __restrict__ ws,
    float* __restrict__ out)
{
    const int bid     = blockIdx.y * gridDim.x + blockIdx.x;
    const int npos    = (int)ws->npos;
    const int ngroups = (int)ws->ngroups;
    const int i0      = blockIdx.x * (256 * IPT);

    __shared__ float4 sEG[MAXCHUNK];
    __shared__ float  sWG[MAXCHUNK];
    __shared__ float  wsum[4];
    const int lane = threadIdx.x & 63;
    const int wid  = threadIdx.x >> 6;

    if (i0 < npos) {                       // block-uniform
        const int per = (ngroups + GY - 1) / GY;
        const int g0  = blockIdx.y * per;
        const int gn  = min(per, ngroups - g0);   // may be <= 0
        for (int t = threadIdx.x; t < gn; t += 256) {
            sEG[t] = *(const float4*)&ws->EG[(g0 + t) * 4];
            sWG[t] = ws->WG[g0 + t];
        }
        __syncthreads();

        float F[IPT], PW[IPT], acc[IPT];
        #pragma unroll
        for (int k = 0; k < IPT; ++k) {
            int i = i0 + k * 256 + threadIdx.x;
            if (i < npos) { float2 s = ws->pos[i]; F[k] = s.x; PW[k] = s.y; }
            else          { F[k] = 0.0f; PW[k] = 0.0f; }
            acc[k] = 0.0f;
        }

        // 4 pairs per (group, k): 4 fma + 3 mul + 1 log2 + 1 fma
        #pragma unroll 2
        for (int g = 0; g < gn; ++g) {
            float4 e = sEG[g];             // broadcast ds_read_b128
            float wg = sWG[g];
            #pragma unroll
            for (int k = 0; k < IPT; ++k) {
                float t0 = fmaf(e.x, F[k], 1.0f);
                float t1 = fmaf(e.y, F[k], 1.0f);
                float t2 = fmaf(e.z, F[k], 1.0f);
                float t3 = fmaf(e.w, F[k], 1.0f);
                float m  = (t0 * t1) * (t2 * t3);   // <= ~4e15, no overflow
                acc[k] = fmaf(__log2f(m), wg, acc[k]);
            }
        }

        float a = 0.0f;
        #pragma unroll
        for (int k = 0; k < IPT; ++k) a = fmaf(acc[k], PW[k], a);
        #pragma unroll
        for (int off = 32; off > 0; off >>= 1)
            a += __shfl_down(a, off, 64);
        if (lane == 0) wsum[wid] = a;
        __syncthreads();
    } else {
        if (threadIdx.x < 4) wsum[threadIdx.x] = 0.0f;
        __syncthreads();
    }

    if (threadIdx.x == 0)
        ws->partials[bid] = (double)(wsum[0] + wsum[1] + wsum[2] + wsum[3]);

    // ticket: last block to arrive does the final reduction
    __shared__ int isLast;
    __threadfence();
    if (threadIdx.x == 0) {
        unsigned int old = atomicAdd(&ws->done, 1u);
        isLast = (old == NBLK - 1) ? 1 : 0;
    }
    __syncthreads();
    if (isLast) {
        const volatile double* vp = (const volatile double*)ws->partials;
        double s = 0.0;
        for (int t = threadIdx.x; t < NBLK; t += 256) s += vp[t];
        #pragma unroll
        for (int off = 32; off > 0; off >>= 1)
            s += __shfl_down(s, off, 64);
        __shared__ double dsum[4];
        if (lane == 0) dsum[wid] = s;
        __syncthreads();
        if (threadIdx.x == 0) {
            double total = dsum[0] + dsum[1] + dsum[2] + dsum[3];
            double denom = (double)ws->npos * (double)ws->nneg;
            out[0] = (float)(total / denom);
        }
    }
}

extern "C" void kernel_launch(void* const* d_in, const int* in_sizes, int n_in,
                              void* d_out, int out_size, void* d_ws, size_t ws_size,
                              hipStream_t stream)
{
    const float* preds  = (const float*)d_in[0];
    const float* sw     = (const float*)d_in[1];
    const int*   labels = (const int*)d_in[2];
    float* out = (float*)d_out;
    Ws* ws = (Ws*)d_ws;

    prep_kernel<<<1, 1024, 0, stream>>>(preds, sw, labels, ws);

    dim3 grid(GX, GY);
    pairs_kernel<<<grid, 256, 0, stream>>>(ws, out);
}

// Round 6
// 21.600 us; speedup vs baseline: 5.1893x; 5.1893x over previous
//
#include <hip/hip_runtime.h>

#define NB 64
#define NC 206
#define N (NB * NC)        // 13184
#define IPT 4              // positives per thread
#define GX 13              // ceil(N / 1024) worst-case positive coverage
#define GY 64              // group-chunk splits
#define NBLK (GX * GY)     // 832
#define MAXG 3328          // worst-case groups: 64 * ceil(206/4)
#define MAXCHUNK 52        // ceil(MAXG / GY)
#define LN2F 0.69314718056f

// Workspace. Poisoned once to 0xAA by the harness; every field we read is
// rewritten by prep/pairs on every call. No zero-init needed anywhere.
struct Ws {
    float2 pos[N];            // compacted positives {exp(-p), w}
    float  EG[MAXG * 4];      // grouped negative exp(p), zero-padded to 4 (16B aligned)
    float  WG[MAXG];          // per-group weight * ln2
    unsigned int npos, nneg, ngroups, pad;
    double partials[NBLK];
};

// ---- deterministic prep: one block per sample row, no atomics ----
__global__ __launch_bounds__(256) void prep_kernel(
    const float* __restrict__ preds,
    const float* __restrict__ sw,
    const int* __restrict__ labels,
    Ws* __restrict__ ws)
{
    const int r    = blockIdx.x;          // this block's row
    const int wave = threadIdx.x >> 6;    // 0..3
    const int lane = threadIdx.x & 63;

    // phase A: ballot-count rows [0, r) to get this row's write bases.
    // labels are L2-resident (52 KB); worst block scans 13K ints.
    int pc = 0, nc = 0, gc = 0;
    for (int rr = wave; rr < r; rr += 4) {
        int rpc = 0, rnc = 0;
        for (int c0 = 0; c0 < NC; c0 += 64) {
            int c = c0 + lane;
            int l = (c < NC) ? labels[rr * NC + c] : -1;
            rpc += __popcll(__ballot(l == 1));
            rnc += __popcll(__ballot(l == 0));
        }
        pc += rpc;
        nc += rnc;
        gc += (rnc + 3) >> 2;
    }
    __shared__ int cnt[3][4];
    if (lane == 0) { cnt[0][wave] = pc; cnt[1][wave] = nc; cnt[2][wave] = gc; }
    __syncthreads();

    // phase B: wave 0 compacts + transforms its own row (206 elems, 4 iters)
    if (wave == 0) {
        const int posBase = cnt[0][0] + cnt[0][1] + cnt[0][2] + cnt[0][3];
        const int negBase = cnt[1][0] + cnt[1][1] + cnt[1][2] + cnt[1][3];
        const int grpBase = cnt[2][0] + cnt[2][1] + cnt[2][2] + cnt[2][3];
        const float w    = sw[r];
        const float wln2 = w * LN2F;
        int pOff = posBase;
        int nIdx = 0;
        for (int c0 = 0; c0 < NC; c0 += 64) {
            int c = c0 + lane;
            bool inb = (c < NC);
            float p = inb ? preds[r * NC + c] : 0.0f;
            int   l = inb ? labels[r * NC + c] : -1;
            unsigned long long balP = __ballot(l == 1);
            unsigned long long balN = __ballot(l == 0);
            unsigned long long pre  = (1ull << lane) - 1ull;
            if (l == 1) {
                int o = pOff + __popcll(balP & pre);
                ws->pos[o] = make_float2(__expf(-p), w);
            }
            if (l == 0) {
                int idx = nIdx + __popcll(balN & pre);
                int g   = grpBase + (idx >> 2);
                ws->EG[g * 4 + (idx & 3)] = __expf(p);
                if ((idx & 3) == 0) ws->WG[g] = wln2;
            }
            pOff += __popcll(balP);
            nIdx += __popcll(balN);
        }
        // zero-pad the row's last group (E=0 -> t=1 -> log contribution 0)
        int fill = nIdx & 3;
        if (fill) {
            int gLast = grpBase + (nIdx >> 2);
            if (lane < 4 - fill) ws->EG[gLast * 4 + fill + lane] = 0.0f;
        }
        // last row's block knows the grand totals
        if (r == NB - 1 && lane == 0) {
            ws->npos    = (unsigned int)pOff;
            ws->nneg    = (unsigned int)(negBase + nIdx);
            ws->ngroups = (unsigned int)(grpBase + ((nIdx + 3) >> 2));
        }
    }
}

// ---- pairs: partial sums into per-block slots, no atomics ----
__global__ __launch_bounds__(256) void pairs_kernel(
    const Ws* __restrict__ ws,
    double* __restrict__ partials)
{
    const int bid     = blockIdx.y * gridDim.x + blockIdx.x;
    const int npos    = (int)ws->npos;
    const int ngroups = (int)ws->ngroups;
    const int i0      = blockIdx.x * (256 * IPT);

    if (i0 >= npos) {                      // block-uniform early-out
        if (threadIdx.x == 0) partials[bid] = 0.0;
        return;
    }

    __shared__ float4 sEG[MAXCHUNK];
    __shared__ float  sWG[MAXCHUNK];
    const int per = (ngroups + GY - 1) / GY;
    const int g0  = blockIdx.y * per;
    const int gn  = min(per, ngroups - g0);    // may be <= 0
    for (int t = threadIdx.x; t < gn; t += 256) {
        sEG[t] = *(const float4*)&ws->EG[(g0 + t) * 4];
        sWG[t] = ws->WG[g0 + t];
    }
    __syncthreads();

    float F[IPT], PW[IPT], acc[IPT];
    #pragma unroll
    for (int k = 0; k < IPT; ++k) {
        int i = i0 + k * 256 + threadIdx.x;
        if (i < npos) { float2 s = ws->pos[i]; F[k] = s.x; PW[k] = s.y; }
        else          { F[k] = 0.0f; PW[k] = 0.0f; }   // t=1 -> log=0
        acc[k] = 0.0f;
    }

    // 4 pairs per (group, k): 4 fma + 3 mul + 1 log2 + 1 fma
    #pragma unroll 2
    for (int g = 0; g < gn; ++g) {
        float4 e = sEG[g];                 // broadcast ds_read_b128
        float wg = sWG[g];
        #pragma unroll
        for (int k = 0; k < IPT; ++k) {
            float t0 = fmaf(e.x, F[k], 1.0f);
            float t1 = fmaf(e.y, F[k], 1.0f);
            float t2 = fmaf(e.z, F[k], 1.0f);
            float t3 = fmaf(e.w, F[k], 1.0f);
            float m  = (t0 * t1) * (t2 * t3);   // <= ~1e14, no overflow
            acc[k] = fmaf(__log2f(m), wg, acc[k]);
        }
    }

    float a = 0.0f;
    #pragma unroll
    for (int k = 0; k < IPT; ++k) a = fmaf(acc[k], PW[k], a);

    #pragma unroll
    for (int off = 32; off > 0; off >>= 1)
        a += __shfl_down(a, off, 64);

    __shared__ float wsum[4];
    const int lane = threadIdx.x & 63;
    const int wid  = threadIdx.x >> 6;
    if (lane == 0) wsum[wid] = a;
    __syncthreads();
    if (threadIdx.x == 0)
        partials[bid] = (double)(wsum[0] + wsum[1] + wsum[2] + wsum[3]);
}

__global__ __launch_bounds__(256) void reduce_kernel(
    const Ws* __restrict__ ws,
    float* __restrict__ out)
{
    double s = 0.0;
    for (int t = threadIdx.x; t < NBLK; t += 256)
        s += ws->partials[t];

    #pragma unroll
    for (int off = 32; off > 0; off >>= 1)
        s += __shfl_down(s, off, 64);

    __shared__ double ds[4];
    const int lane = threadIdx.x & 63;
    const int wid  = threadIdx.x >> 6;
    if (lane == 0) ds[wid] = s;
    __syncthreads();
    if (threadIdx.x == 0) {
        double total = ds[0] + ds[1] + ds[2] + ds[3];
        double denom = (double)ws->npos * (double)ws->nneg;
        out[0] = (float)(total / denom);
    }
}

extern "C" void kernel_launch(void* const* d_in, const int* in_sizes, int n_in,
                              void* d_out, int out_size, void* d_ws, size_t ws_size,
                              hipStream_t stream)
{
    const float* preds  = (const float*)d_in[0];
    const float* sw     = (const float*)d_in[1];
    const int*   labels = (const int*)d_in[2];
    float* out = (float*)d_out;
    Ws* ws = (Ws*)d_ws;

    prep_kernel<<<NB, 256, 0, stream>>>(preds, sw, labels, ws);

    dim3 grid(GX, GY);
    pairs_kernel<<<grid, 256, 0, stream>>>(ws, ws->partials);

    reduce_kernel<<<1, 256, 0, stream>>>(ws, out);
}